// Round 4
// baseline (110.140 us; speedup 1.0000x reference)
//
#include <hip/hip_runtime.h>
#include <math.h>

typedef __attribute__((ext_vector_type(8))) short bf16x8;
typedef __attribute__((ext_vector_type(4))) float f32x4;

#define W1S_OFF 0
#define W2S_OFF 262144
#define MZ_OFF  393216          // motifs_z, [p=m*64+c][16] bf16 (12 used, 4 pad)

__device__ __forceinline__ ushort f2bf(float x){
    union{float f; unsigned u;} v; v.f = x;
    unsigned r = v.u + 0x7fffu + ((v.u >> 16) & 1u);
    return (ushort)(r >> 16);
}
__device__ __forceinline__ float bf2f(ushort u){
    union{unsigned i; float f;} v; v.i = ((unsigned)u) << 16; return v.f;
}

// Pack W1 (512x512) and W2 (512x256) into bf16 MFMA-B-fragment order.
// B-frag layout: ws[((tn_g*16 + tk)*64 + lane)*8 + j] = W[k][n],
//   k = tk*32 + (lane>>4)*8 + j,  n = tn_g*16 + (lane&15).
// This version reads W coalesced (thread = k*N + n) and scatter-writes into L2.
__global__ __launch_bounds__(256) void prep_kernel(
    const float* __restrict__ W1, const float* __restrict__ W2,
    const float* __restrict__ motifs, ushort* __restrict__ ws)
{
    int idx = blockIdx.x * 256 + threadIdx.x;
    if (idx < 262144) {                        // W1: idx = k*512 + n
        int k = idx >> 9, n = idx & 511;
        int tk = k >> 5, j = k & 7, hig = (k >> 3) & 3;
        int tn = n >> 4, lo = n & 15;
        int lane = hig * 16 + lo;
        ws[W1S_OFF + (((tn*16 + tk)*64 + lane)*8 + j)] = f2bf(W1[idx]);
    } else if (idx < 393216) {                 // W2: i = k*256 + n
        int i = idx - 262144;
        int k = i >> 8, n = i & 255;
        int tk = k >> 5, j = k & 7, hig = (k >> 3) & 3;
        int tn = n >> 4, lo = n & 15;
        int lane = hig * 16 + lo;
        ws[W2S_OFF + (((tn*16 + tk)*64 + lane)*8 + j)] = f2bf(W2[i]);
    } else if (idx < 393216 + 512) {
        int p = idx - 393216;                  // p = m*64 + c
        const float* mp = motifs + p*12;
        float v[12]; float sm = 0.f;
        #pragma unroll
        for (int l = 0; l < 12; ++l){ v[l] = mp[l]; sm += v[l]; }
        float mean = sm * (1.f/12.f), sq = 0.f;
        #pragma unroll
        for (int l = 0; l < 12; ++l){ float d = v[l]-mean; sq = fmaf(d,d,sq); }
        float inv = 1.f / (sqrtf(sq*(1.f/12.f)) + 1e-8f);
        #pragma unroll
        for (int l = 0; l < 12; ++l) ws[MZ_OFF + p*16 + l] = f2bf((v[l]-mean)*inv);
        #pragma unroll
        for (int l = 12; l < 16; ++l) ws[MZ_OFF + p*16 + l] = 0;
    }
}

// Swizzled byte offset into the [64][512] bf16 LDS tile (conflict-free b128 A-frag reads)
#define SWZ(r, k) (((((r) << 9) + (k)) << 1) ^ (((r) & 7) << 4))

// One block = 64 rows. Phase A (fp32 VALU) -> flat bf16 in LDS -> MFMA GEMM1 ->
// gelu -> LN -> hn bf16 in LDS -> MFMA GEMM2 -> nontemporal stores to out.
__global__ __launch_bounds__(512, 4) void fused_kernel(
    const float* __restrict__ x, const ushort* __restrict__ ws,
    const float* __restrict__ b1, const float* __restrict__ gamma,
    const float* __restrict__ beta, const float* __restrict__ b2,
    float* __restrict__ out)
{
    __shared__ __align__(16) ushort fl[64*512];   // 64 KB: flat, later hn
    __shared__ float part[64][8][2];              // per-wave LN partials
    __shared__ float mu_s[64];
    __shared__ float rs_s[64];

    const int t  = threadIdx.x;
    const int g0 = blockIdx.x * 64;               // global row base (row = bi*4096+s)

    const int w    = t >> 6;          // wave 0..7
    const int lane = t & 63;
    const int hi   = lane >> 4;
    const int lo   = lane & 15;
    const int n0   = w * 64;

    // ---------------- Phase A: motif correlation -> flat (bf16, swizzled) ----------------
    {
        const int c  = t & 63;
        const int rg = t >> 6;                    // 0..7 -> rows rg*8 .. rg*8+7
        const ushort* mzw = ws + MZ_OFF;
        for (int rq = 0; rq < 2; ++rq) {
            float wz[4][12];
            #pragma unroll
            for (int q = 0; q < 4; ++q) {
                const int r  = rg*8 + rq*4 + q;
                const int gr = g0 + r;
                const int sb = gr & 4095;                 // position within batch
                const size_t base = (size_t)(gr - sb) * 64 + c;
                float wv[12]; float sm = 0.f;
                #pragma unroll
                for (int l = 0; l < 12; ++l) {
                    int sw = sb - 11 + l; sw = sw < 0 ? 0 : sw;
                    wv[l] = x[base + (size_t)sw * 64]; sm += wv[l];
                }
                float mean = sm * (1.f/12.f), sq = 0.f;
                #pragma unroll
                for (int l = 0; l < 12; ++l){ float d = wv[l]-mean; sq = fmaf(d,d,sq); }
                float inv = 1.f / (sqrtf(sq*(1.f/12.f)) + 1e-8f);
                #pragma unroll
                for (int l = 0; l < 12; ++l) wz[q][l] = (wv[l]-mean)*inv;
            }
            for (int m = 0; m < 8; ++m) {
                const uint* mp32 = (const uint*)(mzw + (m*64 + c)*16);
                float mzv[12];
                #pragma unroll
                for (int h = 0; h < 6; ++h) {
                    uint u = mp32[h];
                    mzv[2*h]   = bf2f((ushort)(u & 0xffffu));
                    mzv[2*h+1] = bf2f((ushort)(u >> 16));
                }
                #pragma unroll
                for (int q = 0; q < 4; ++q) {
                    float dot = 0.f;
                    #pragma unroll
                    for (int l = 0; l < 12; ++l) dot = fmaf(wz[q][l], mzv[l], dot);
                    float sim = dot * (1.f/12.f);
                    float rv  = fmaxf(sim, 0.f);
                    float rv2 = rv * rv;
                    const int r = rg*8 + rq*4 + q, k = m*64 + c;
                    *(ushort*)((char*)fl + SWZ(r, k)) = f2bf(rv2*rv2);
                }
            }
        }
    }

    // ---------------- GEMM1: [64 x 512] x [512 x 512], wave n-slice = 64 ----------------
    const ushort* ws1 = ws + W1S_OFF;
    bf16x8 bc[4], bn[4];
    #pragma unroll
    for (int tn = 0; tn < 4; ++tn)    // prefetch tk=0 B-frags before the barrier
        bc[tn] = *(const bf16x8*)(ws1 + (size_t)((w*4 + tn)*16 + 0)*512 + lane*8);

    __syncthreads();

    f32x4 acc[4][4];
    #pragma unroll
    for (int mt = 0; mt < 4; ++mt)
        #pragma unroll
        for (int tn = 0; tn < 4; ++tn)
            acc[mt][tn] = (f32x4){0.f,0.f,0.f,0.f};

    #pragma unroll
    for (int tk = 0; tk < 16; ++tk) {
        if (tk < 15) {
            #pragma unroll
            for (int tn = 0; tn < 4; ++tn)
                bn[tn] = *(const bf16x8*)(ws1 + (size_t)((w*4 + tn)*16 + tk + 1)*512 + lane*8);
        }
        bf16x8 a[4];
        #pragma unroll
        for (int mt = 0; mt < 4; ++mt)
            a[mt] = *(const bf16x8*)((char*)fl + SWZ(mt*16 + lo, tk*32 + hi*8));
        #pragma unroll
        for (int tn = 0; tn < 4; ++tn)
            #pragma unroll
            for (int mt = 0; mt < 4; ++mt)
                acc[mt][tn] = __builtin_amdgcn_mfma_f32_16x16x32_bf16(a[mt], bc[tn], acc[mt][tn], 0, 0, 0);
        #pragma unroll
        for (int tn = 0; tn < 4; ++tn) bc[tn] = bn[tn];
    }

    // ---------------- bias + exact gelu (in regs) ----------------
    {
        float b1v[4];
        #pragma unroll
        for (int tn = 0; tn < 4; ++tn) b1v[tn] = b1[n0 + tn*16 + lo];
        #pragma unroll
        for (int mt = 0; mt < 4; ++mt)
            #pragma unroll
            for (int tn = 0; tn < 4; ++tn)
                #pragma unroll
                for (int e = 0; e < 4; ++e) {
                    float v = acc[mt][tn][e] + b1v[tn];
                    acc[mt][tn][e] = 0.5f * v * (1.f + erff(v * 0.70710678118654752f));
                }
    }

    // ---------------- LayerNorm: partials -> stats -> normalize -> hn bf16 LDS ----------------
    #pragma unroll
    for (int mt = 0; mt < 4; ++mt)
        #pragma unroll
        for (int e = 0; e < 4; ++e) {
            float s1 = 0.f, s2 = 0.f;
            #pragma unroll
            for (int tn = 0; tn < 4; ++tn) {
                float g = acc[mt][tn][e];
                s1 += g; s2 = fmaf(g, g, s2);
            }
            #pragma unroll
            for (int o = 1; o < 16; o <<= 1) {
                s1 += __shfl_xor(s1, o);
                s2 += __shfl_xor(s2, o);
            }
            if (lo == 0) {
                int row = mt*16 + hi*4 + e;
                part[row][w][0] = s1;
                part[row][w][1] = s2;
            }
        }
    __syncthreads();
    if (t < 64) {
        float s1 = 0.f, s2 = 0.f;
        #pragma unroll
        for (int ww = 0; ww < 8; ++ww) { s1 += part[t][ww][0]; s2 += part[t][ww][1]; }
        float mu  = s1 * (1.f/512.f);
        float var = s2 * (1.f/512.f) - mu*mu;
        mu_s[t] = mu;
        rs_s[t] = rsqrtf(var + 1e-5f);
    }
    __syncthreads();
    {
        float gv[4], bv[4];
        #pragma unroll
        for (int tn = 0; tn < 4; ++tn) {
            gv[tn] = gamma[n0 + tn*16 + lo];
            bv[tn] = beta[n0 + tn*16 + lo];
        }
        #pragma unroll
        for (int mt = 0; mt < 4; ++mt)
            #pragma unroll
            for (int e = 0; e < 4; ++e) {
                int row = mt*16 + hi*4 + e;
                float mu = mu_s[row], rs = rs_s[row];
                #pragma unroll
                for (int tn = 0; tn < 4; ++tn) {
                    float hn = (acc[mt][tn][e] - mu) * rs * gv[tn] + bv[tn];
                    int col = n0 + tn*16 + lo;
                    *(ushort*)((char*)fl + SWZ(row, col)) = f2bf(hn);
                }
            }
    }

    // ---------------- GEMM2: [64 x 512] x [512 x 256], wave n-slice = 32 ----------------
    const ushort* ws2 = ws + W2S_OFF;
    bf16x8 bc2[2], bn2[2];
    #pragma unroll
    for (int tn = 0; tn < 2; ++tn)    // prefetch tk=0 before the barrier
        bc2[tn] = *(const bf16x8*)(ws2 + (size_t)((w*2 + tn)*16 + 0)*512 + lane*8);

    __syncthreads();

    f32x4 acc2[4][2];
    #pragma unroll
    for (int mt = 0; mt < 4; ++mt)
        #pragma unroll
        for (int tn = 0; tn < 2; ++tn)
            acc2[mt][tn] = (f32x4){0.f,0.f,0.f,0.f};

    #pragma unroll
    for (int tk = 0; tk < 16; ++tk) {
        if (tk < 15) {
            #pragma unroll
            for (int tn = 0; tn < 2; ++tn)
                bn2[tn] = *(const bf16x8*)(ws2 + (size_t)((w*2 + tn)*16 + tk + 1)*512 + lane*8);
        }
        bf16x8 a[4];
        #pragma unroll
        for (int mt = 0; mt < 4; ++mt)
            a[mt] = *(const bf16x8*)((char*)fl + SWZ(mt*16 + lo, tk*32 + hi*8));
        #pragma unroll
        for (int tn = 0; tn < 2; ++tn)
            #pragma unroll
            for (int mt = 0; mt < 4; ++mt)
                acc2[mt][tn] = __builtin_amdgcn_mfma_f32_16x16x32_bf16(a[mt], bc2[tn], acc2[mt][tn], 0, 0, 0);
        #pragma unroll
        for (int tn = 0; tn < 2; ++tn) bc2[tn] = bn2[tn];
    }

    // ---------------- + b2 -> out (non-temporal: keep W resident in L2) ----------------
    {
        const int n2 = w * 32;
        float b2v[2];
        #pragma unroll
        for (int tn = 0; tn < 2; ++tn) b2v[tn] = b2[n2 + tn*16 + lo];
        #pragma unroll
        for (int mt = 0; mt < 4; ++mt)
            #pragma unroll
            for (int tn = 0; tn < 2; ++tn) {
                int col = n2 + tn*16 + lo;
                #pragma unroll
                for (int e = 0; e < 4; ++e) {
                    int row = mt*16 + hi*4 + e;
                    __builtin_nontemporal_store(acc2[mt][tn][e] + b2v[tn],
                                                &out[(size_t)(g0 + row) * 256 + col]);
                }
            }
    }
}

extern "C" void kernel_launch(void* const* d_in, const int* in_sizes, int n_in,
                              void* d_out, int out_size, void* d_ws, size_t ws_size,
                              hipStream_t stream) {
    const float* x      = (const float*)d_in[0];
    const float* motifs = (const float*)d_in[1];
    const float* W1     = (const float*)d_in[2];
    const float* b1     = (const float*)d_in[3];
    const float* gamma  = (const float*)d_in[4];
    const float* beta   = (const float*)d_in[5];
    const float* W2     = (const float*)d_in[6];
    const float* b2     = (const float*)d_in[7];
    float* out = (float*)d_out;
    ushort* ws = (ushort*)d_ws;

    prep_kernel<<<(393216 + 512 + 255) / 256, 256, 0, stream>>>(W1, W2, motifs, ws);
    fused_kernel<<<512, 512, 0, stream>>>(x, ws, b1, gamma, beta, b2, out);
}